// Round 15
// baseline (149.825 us; speedup 1.0000x reference)
//
#include <hip/hip_runtime.h>

constexpr int IN_F  = 128;
constexpr int OUT_F = 64;
constexpr int NB_BLOCKS = 256;   // edge-chunk blocks; == colscan block size
constexpr int BIN_SHIFT = 6;     // 64 nodes per bin
constexpr int MAX_BINS  = 1024;  // N <= 65536
constexpr int BIN_CAP   = 8192;  // binsort LDS capacity (words)

using bf16x8 = __attribute__((ext_vector_type(8))) short;  // 8 bf16 in 4 VGPRs
using f32x4  = __attribute__((ext_vector_type(4))) float;

__device__ inline short f2bf(float f) {  // RNE float->bf16
    unsigned u = __builtin_bit_cast(unsigned, f);
    u += 0x7fffu + ((u >> 16) & 1u);
    return (short)(u >> 16);
}
__device__ inline float bf2f(unsigned short u) {
    unsigned x = ((unsigned)u) << 16;
    return __builtin_bit_cast(float, x);
}

// ---------------- GEMM: h(bf16) = feats @ weight via bf16 MFMA ----------------
__global__ __launch_bounds__(256) void gemm_kernel(
        const float* __restrict__ feats, const float* __restrict__ weight,
        unsigned short* __restrict__ h, int n_nodes) {
    __shared__ short wbT[OUT_F][IN_F + 8];  // bf16, transposed, pad 8 halfs

    for (int idx = threadIdx.x; idx < IN_F * OUT_F; idx += 256)
        wbT[idx & 63][idx >> 6] = f2bf(weight[idx]);   // coalesced read, LDS transpose write
    __syncthreads();

    const int lane  = threadIdx.x & 63;
    const int wid   = threadIdx.x >> 6;
    const int arow  = lane & 15;
    const int kg    = lane >> 4;
    const int node0 = blockIdx.x * 64 + wid * 16;

    const int an = min(node0 + arow, n_nodes - 1);  // clamp (invalid rows not stored)
    const float* ap = feats + (size_t)an * IN_F;

    f32x4 acc[4] = {{0,0,0,0},{0,0,0,0},{0,0,0,0},{0,0,0,0}};

    #pragma unroll
    for (int ks = 0; ks < 4; ++ks) {                 // K-step of 32
        const int kbase = ks * 32 + kg * 8;
        const float4 a0 = *reinterpret_cast<const float4*>(ap + kbase);
        const float4 a1 = *reinterpret_cast<const float4*>(ap + kbase + 4);
        bf16x8 a;
        a[0] = f2bf(a0.x); a[1] = f2bf(a0.y); a[2] = f2bf(a0.z); a[3] = f2bf(a0.w);
        a[4] = f2bf(a1.x); a[5] = f2bf(a1.y); a[6] = f2bf(a1.z); a[7] = f2bf(a1.w);
        #pragma unroll
        for (int nt = 0; nt < 4; ++nt) {
            const bf16x8 b = *reinterpret_cast<const bf16x8*>(&wbT[nt * 16 + (lane & 15)][kbase]);
            acc[nt] = __builtin_amdgcn_mfma_f32_16x16x32_bf16(a, b, acc[nt], 0, 0, 0);
        }
    }

    #pragma unroll
    for (int nt = 0; nt < 4; ++nt) {
        #pragma unroll
        for (int r = 0; r < 4; ++r) {
            const int n = node0 + (lane >> 4) * 4 + r;   // C row
            if (n < n_nodes)
                h[(size_t)n * OUT_F + nt * 16 + (lane & 15)] = (unsigned short)f2bf(acc[nt][r]);
        }
    }
}

// ---------------- B1: per-chunk LDS histogram over bins ----------------
__global__ void hist_kernel(const int* __restrict__ dst, int* __restrict__ histmat,
                            int E, int nbins) {
    __shared__ int hl[MAX_BINS];
    const int k = blockIdx.x;
    const int chunk = (E + NB_BLOCKS - 1) / NB_BLOCKS;
    const int beg = k * chunk, end = min(E, beg + chunk);
    for (int i = threadIdx.x; i < nbins; i += blockDim.x) hl[i] = 0;
    __syncthreads();
    for (int e = beg + threadIdx.x; e < end; e += blockDim.x)
        atomicAdd(&hl[dst[e] >> BIN_SHIFT], 1);
    __syncthreads();
    for (int i = threadIdx.x; i < nbins; i += blockDim.x)
        histmat[k * nbins + i] = hl[i];
}

// ---------------- S1: per-bin exclusive scan over the 256 chunks ----------------
__global__ void colscan_kernel(int* __restrict__ histmat, int* __restrict__ tot, int nbins) {
    __shared__ int s[NB_BLOCKS];
    const int b = blockIdx.x;
    const int t = threadIdx.x;
    const int v = histmat[t * nbins + b];
    s[t] = v;
    __syncthreads();
    for (int off = 1; off < NB_BLOCKS; off <<= 1) {
        const int u = (t >= off) ? s[t - off] : 0;
        __syncthreads();
        s[t] += u;
        __syncthreads();
    }
    histmat[t * nbins + b] = s[t] - v;  // exclusive over blocks
    if (t == NB_BLOCKS - 1) tot[b] = s[t];
}

// ---------------- S2: exclusive scan of bin totals ----------------
__global__ void binscan_kernel(const int* __restrict__ tot, int* __restrict__ binbase,
                               int nbins, int E) {
    __shared__ int s[MAX_BINS];
    const int t = threadIdx.x;
    const int v = (t < nbins) ? tot[t] : 0;
    s[t] = v;
    __syncthreads();
    for (int off = 1; off < MAX_BINS; off <<= 1) {
        const int u = (t >= off) ? s[t - off] : 0;
        __syncthreads();
        s[t] += u;
        __syncthreads();
    }
    if (t < nbins) binbase[t] = s[t] - v;
    if (t == 0) binbase[nbins] = E;
}

// ---------------- B2: deterministic scatter into bins (LDS cursors only) ----------------
__global__ void scatter_kernel(const int* __restrict__ src, const int* __restrict__ dst,
                               const int* __restrict__ colscan, const int* __restrict__ binbase,
                               unsigned int* __restrict__ bucket, int E, int nbins) {
    __shared__ int cur[MAX_BINS];
    const int k = blockIdx.x;
    for (int i = threadIdx.x; i < nbins; i += blockDim.x)
        cur[i] = binbase[i] + colscan[k * nbins + i];
    __syncthreads();
    const int chunk = (E + NB_BLOCKS - 1) / NB_BLOCKS;
    const int beg = k * chunk, end = min(E, beg + chunk);
    for (int e = beg + threadIdx.x; e < end; e += blockDim.x) {
        const int d = dst[e];
        const int pos = atomicAdd(&cur[d >> BIN_SHIFT], 1);
        bucket[pos] = ((unsigned)(d & 63) << 16) | (unsigned)src[e];  // src < 65536
    }
}

// ---------------- B3: per-bin counting sort (in place) -> per-node CSR offs ----------------
__global__ void binsort_kernel(unsigned int* __restrict__ bucket,
                               const int* __restrict__ binbase,
                               int* __restrict__ offs, int N, int E, int nbins) {
    __shared__ unsigned buf[BIN_CAP];  // 32 KB
    __shared__ int cnt64[64];
    __shared__ int off64[64];
    const int b    = blockIdx.x;
    const int base = binbase[b], end = binbase[b + 1];
    const int cnt  = end - base;

    for (int i = threadIdx.x; i < cnt; i += 256) buf[i] = bucket[base + i];
    if (threadIdx.x < 64) cnt64[threadIdx.x] = 0;
    __syncthreads();
    for (int i = threadIdx.x; i < cnt; i += 256)
        atomicAdd(&cnt64[buf[i] >> 16], 1);
    __syncthreads();

    int v = 0;
    if (threadIdx.x < 64) { v = cnt64[threadIdx.x]; off64[threadIdx.x] = v; }
    __syncthreads();
    for (int off = 1; off < 64; off <<= 1) {
        int u = 0;
        if (threadIdx.x >= off && threadIdx.x < 64) u = off64[threadIdx.x - off];
        __syncthreads();
        if (threadIdx.x < 64) off64[threadIdx.x] += u;
        __syncthreads();
    }
    if (threadIdx.x < 64) {
        const int excl = off64[threadIdx.x] - v;
        const int node = (b << BIN_SHIFT) + threadIdx.x;
        if (node < N) offs[node] = base + excl;
        off64[threadIdx.x] = excl;  // becomes the scatter cursor
    }
    __syncthreads();

    for (int i = threadIdx.x; i < cnt; i += 256) {
        const unsigned wdv = buf[i];
        const int pos = atomicAdd(&off64[wdv >> 16], 1);
        bucket[base + pos] = wdv;
    }
    if (b == nbins - 1 && threadIdx.x == 0) offs[N] = E;
}

// ---------------- C: dual-node pull gather (bf16 h) + bias + ReLU ----------------
// Two nodes per wave, interleaved 8-deep streams -> 16 loads in flight.
__global__ __launch_bounds__(256) void gather_kernel(
        const unsigned short* __restrict__ h, const unsigned int* __restrict__ bucket,
        const int* __restrict__ offs, const float* __restrict__ bias,
        float* __restrict__ out, int N) {
    const int lane   = threadIdx.x & 63;
    const int gwave  = (blockIdx.x * blockDim.x + threadIdx.x) >> 6;
    const int nwaves = (gridDim.x * blockDim.x) >> 6;
    const float b = bias[lane];

    for (int n0 = gwave * 2; n0 < N; n0 += nwaves * 2) {
        const int n1 = n0 + 1;
        const bool has1 = (n1 < N);
        const int beg0 = offs[n0],  end0 = offs[n0 + 1];
        const int beg1 = has1 ? end0 : 0, end1 = has1 ? offs[n0 + 2] : 0;
        float acc0 = 0.f, acc1 = 0.f;
        int i0 = beg0, i1 = beg1;

        // interleaved main loop: 16 h-row loads in flight
        while (i0 + 8 <= end0 && i1 + 8 <= end1) {
            const unsigned a0 = bucket[i0 + 0], a1 = bucket[i0 + 1], a2 = bucket[i0 + 2], a3 = bucket[i0 + 3];
            const unsigned a4 = bucket[i0 + 4], a5 = bucket[i0 + 5], a6 = bucket[i0 + 6], a7 = bucket[i0 + 7];
            const unsigned c0 = bucket[i1 + 0], c1 = bucket[i1 + 1], c2 = bucket[i1 + 2], c3 = bucket[i1 + 3];
            const unsigned c4 = bucket[i1 + 4], c5 = bucket[i1 + 5], c6 = bucket[i1 + 6], c7 = bucket[i1 + 7];
            const unsigned short p0 = h[(size_t)(a0 & 0xffffu) * OUT_F + lane];
            const unsigned short p1 = h[(size_t)(a1 & 0xffffu) * OUT_F + lane];
            const unsigned short p2 = h[(size_t)(a2 & 0xffffu) * OUT_F + lane];
            const unsigned short p3 = h[(size_t)(a3 & 0xffffu) * OUT_F + lane];
            const unsigned short p4 = h[(size_t)(a4 & 0xffffu) * OUT_F + lane];
            const unsigned short p5 = h[(size_t)(a5 & 0xffffu) * OUT_F + lane];
            const unsigned short p6 = h[(size_t)(a6 & 0xffffu) * OUT_F + lane];
            const unsigned short p7 = h[(size_t)(a7 & 0xffffu) * OUT_F + lane];
            const unsigned short q0 = h[(size_t)(c0 & 0xffffu) * OUT_F + lane];
            const unsigned short q1 = h[(size_t)(c1 & 0xffffu) * OUT_F + lane];
            const unsigned short q2 = h[(size_t)(c2 & 0xffffu) * OUT_F + lane];
            const unsigned short q3 = h[(size_t)(c3 & 0xffffu) * OUT_F + lane];
            const unsigned short q4 = h[(size_t)(c4 & 0xffffu) * OUT_F + lane];
            const unsigned short q5 = h[(size_t)(c5 & 0xffffu) * OUT_F + lane];
            const unsigned short q6 = h[(size_t)(c6 & 0xffffu) * OUT_F + lane];
            const unsigned short q7 = h[(size_t)(c7 & 0xffffu) * OUT_F + lane];
            acc0 += bf2f(p0); acc0 += bf2f(p1); acc0 += bf2f(p2); acc0 += bf2f(p3);
            acc0 += bf2f(p4); acc0 += bf2f(p5); acc0 += bf2f(p6); acc0 += bf2f(p7);
            acc1 += bf2f(q0); acc1 += bf2f(q1); acc1 += bf2f(q2); acc1 += bf2f(q3);
            acc1 += bf2f(q4); acc1 += bf2f(q5); acc1 += bf2f(q6); acc1 += bf2f(q7);
            i0 += 8; i1 += 8;
        }
        // drain stream 0
        for (; i0 + 8 <= end0; i0 += 8) {
            const unsigned a0 = bucket[i0 + 0], a1 = bucket[i0 + 1], a2 = bucket[i0 + 2], a3 = bucket[i0 + 3];
            const unsigned a4 = bucket[i0 + 4], a5 = bucket[i0 + 5], a6 = bucket[i0 + 6], a7 = bucket[i0 + 7];
            const unsigned short p0 = h[(size_t)(a0 & 0xffffu) * OUT_F + lane];
            const unsigned short p1 = h[(size_t)(a1 & 0xffffu) * OUT_F + lane];
            const unsigned short p2 = h[(size_t)(a2 & 0xffffu) * OUT_F + lane];
            const unsigned short p3 = h[(size_t)(a3 & 0xffffu) * OUT_F + lane];
            const unsigned short p4 = h[(size_t)(a4 & 0xffffu) * OUT_F + lane];
            const unsigned short p5 = h[(size_t)(a5 & 0xffffu) * OUT_F + lane];
            const unsigned short p6 = h[(size_t)(a6 & 0xffffu) * OUT_F + lane];
            const unsigned short p7 = h[(size_t)(a7 & 0xffffu) * OUT_F + lane];
            acc0 += bf2f(p0); acc0 += bf2f(p1); acc0 += bf2f(p2); acc0 += bf2f(p3);
            acc0 += bf2f(p4); acc0 += bf2f(p5); acc0 += bf2f(p6); acc0 += bf2f(p7);
        }
        for (; i0 < end0; ++i0)
            acc0 += bf2f(h[(size_t)(bucket[i0] & 0xffffu) * OUT_F + lane]);
        // drain stream 1
        for (; i1 + 8 <= end1; i1 += 8) {
            const unsigned c0 = bucket[i1 + 0], c1 = bucket[i1 + 1], c2 = bucket[i1 + 2], c3 = bucket[i1 + 3];
            const unsigned c4 = bucket[i1 + 4], c5 = bucket[i1 + 5], c6 = bucket[i1 + 6], c7 = bucket[i1 + 7];
            const unsigned short q0 = h[(size_t)(c0 & 0xffffu) * OUT_F + lane];
            const unsigned short q1 = h[(size_t)(c1 & 0xffffu) * OUT_F + lane];
            const unsigned short q2 = h[(size_t)(c2 & 0xffffu) * OUT_F + lane];
            const unsigned short q3 = h[(size_t)(c3 & 0xffffu) * OUT_F + lane];
            const unsigned short q4 = h[(size_t)(c4 & 0xffffu) * OUT_F + lane];
            const unsigned short q5 = h[(size_t)(c5 & 0xffffu) * OUT_F + lane];
            const unsigned short q6 = h[(size_t)(c6 & 0xffffu) * OUT_F + lane];
            const unsigned short q7 = h[(size_t)(c7 & 0xffffu) * OUT_F + lane];
            acc1 += bf2f(q0); acc1 += bf2f(q1); acc1 += bf2f(q2); acc1 += bf2f(q3);
            acc1 += bf2f(q4); acc1 += bf2f(q5); acc1 += bf2f(q6); acc1 += bf2f(q7);
        }
        for (; i1 < end1; ++i1)
            acc1 += bf2f(h[(size_t)(bucket[i1] & 0xffffu) * OUT_F + lane]);

        out[(size_t)n0 * OUT_F + lane] = fmaxf(acc0 + b, 0.f);
        if (has1) out[(size_t)n1 * OUT_F + lane] = fmaxf(acc1 + b, 0.f);
    }
}

extern "C" void kernel_launch(void* const* d_in, const int* in_sizes, int n_in,
                              void* d_out, int out_size, void* d_ws, size_t ws_size,
                              hipStream_t stream) {
    const float* feats  = (const float*)d_in[0];
    const float* weight = (const float*)d_in[1];
    const float* bias   = (const float*)d_in[2];
    const int*   src    = (const int*)d_in[3];
    const int*   dst    = (const int*)d_in[4];
    float* out = (float*)d_out;

    const int N = in_sizes[0] / IN_F;
    const int E = in_sizes[3];
    const int nbins = (N + 63) >> BIN_SHIFT;  // 782 for N=50000

    // workspace layout (~11 MB)
    unsigned short* h = (unsigned short*)d_ws;              // N*64 bf16
    unsigned* bucket  = (unsigned*)(h + (size_t)N * OUT_F); // E words
    int*      histmat = (int*)(bucket + E);                 // NB_BLOCKS * nbins
    int*      tot     = histmat + NB_BLOCKS * nbins;        // nbins
    int*      binbase = tot + nbins;                        // nbins + 1
    int*      offs    = binbase + nbins + 1;                // N + 1

    gemm_kernel<<<(N + 63) / 64, 256, 0, stream>>>(feats, weight, h, N);
    hist_kernel<<<NB_BLOCKS, 256, 0, stream>>>(dst, histmat, E, nbins);
    colscan_kernel<<<nbins, NB_BLOCKS, 0, stream>>>(histmat, tot, nbins);
    binscan_kernel<<<1, MAX_BINS, 0, stream>>>(tot, binbase, nbins, E);
    scatter_kernel<<<NB_BLOCKS, 256, 0, stream>>>(src, dst, histmat, binbase, bucket, E, nbins);
    binsort_kernel<<<nbins, 256, 0, stream>>>(bucket, binbase, offs, N, E, nbins);
    // 2048 x 256 = 8192 waves = full residency; writes every out row (no memset needed)
    gather_kernel<<<2048, 256, 0, stream>>>(h, bucket, offs, bias, out, N);
}